// Round 6
// baseline (503.788 us; speedup 1.0000x reference)
//
#include <hip/hip_runtime.h>

// LaterallyConnectedLayer: B=16, NUM_FM=32, N_REPL=4, C=128, H=W=56, K_SZ=5
// Algebra:
//  - softmax map sums to 1 -> first conv never affects winners -> skipped
//  - winner sparsity: K_change and final conv only touch 32 of 128 channels
//  - padding = index remaps; activations in zero-ring-padded [60][64] frames
// R5: root cause of R2/R3 found -- Kc_b was allocated 409,600 but indexed as
//     1,638,400 ([b][g][a][25]) -> OOB atomics corrupted W2/Abf/Sb.
//     Fix: k3_mfma accumulates directly into Kc[c][a][25] (409,600, matches
//     memset); k4 reads it directly (cmask dropped). MFMA k3 algebra verified.

typedef __attribute__((ext_vector_type(8))) short short8;
typedef __attribute__((ext_vector_type(4))) float floatx4;

#define EPSF 1e-10f

__device__ __forceinline__ int map60(int r) {
  return r < 4 ? 5 - r : (r < 56 ? r - 2 : 109 - r);
}
__device__ __forceinline__ unsigned short f2bf(float x) {
  unsigned int u = __float_as_uint(x);
  u += 0x7fff + ((u >> 16) & 1);
  return (unsigned short)(u >> 16);
}
__device__ __forceinline__ float bf2f(unsigned int h) {
  return __uint_as_float((h & 0xffffu) << 16);
}

// k1: Abf[128 + bc*3840 + p] = bf16 zero-ring relu(A_sym + 0.1*noise);
//     s[bc] = fp32 interior sum (pre-rounding)
__global__ __launch_bounds__(256) void k1_build(const float* __restrict__ A,
                                                const float* __restrict__ noise,
                                                unsigned short* __restrict__ Abf,
                                                float* __restrict__ s) {
  int bc = blockIdx.x;
  int b = bc >> 7, c = bc & 127;
  int fm = c & 31;
  const float* Abase = A + (size_t)(b * 32 + fm) * 3136;
  const float* nz = noise + (size_t)bc * 3136;
  unsigned short* outb = Abf + 128 + (size_t)bc * 3840;
  float local = 0.f;
  for (int idx = threadIdx.x; idx < 3840; idx += 256) {
    int r = idx >> 6, col = idx & 63;
    int h = r - 2, w = col - 2;
    float v = 0.f;
    if ((unsigned)h < 56u && (unsigned)w < 56u) {
      int hh = h < 2 ? 3 - h : (h >= 54 ? 107 - h : h);
      int ww = w < 2 ? 3 - w : (w >= 54 ? 107 - w : w);
      v = fmaxf(Abase[hh * 56 + ww] + 0.1f * nz[h * 56 + w], 0.f);
      local += v;
    }
    outb[idx] = f2bf(v);
  }
  int lane = threadIdx.x & 63, wid = threadIdx.x >> 6;
  float v = local;
  for (int off = 32; off; off >>= 1) v += __shfl_down(v, off, 64);
  __shared__ float red[4];
  if (lane == 0) red[wid] = v;
  __syncthreads();
  if (threadIdx.x == 0) s[bc] = red[0] + red[1] + red[2] + red[3];
}

// k2: winners + zero Abf guard rings (128 elements each end)
__global__ __launch_bounds__(512) void k2_winners(const float* __restrict__ s,
                                                  int* __restrict__ fm_idx,
                                                  unsigned short* __restrict__ Abf) {
  int t = threadIdx.x;
  {
    int b = t >> 5, f = t & 31;
    float best = s[b * 128 + f];
    int bn = 0;
    for (int n = 1; n < 4; n++) {
      float v = s[b * 128 + n * 32 + f];
      if (v > best) { best = v; bn = n; }
    }
    fm_idx[t] = bn * 32 + f;
  }
  if (t < 128) Abf[t] = 0;
  if (t >= 384) Abf[128 + 7864320 + (t - 384)] = 0;
}

// k2c: Sb[b][di][g][3840] = Abf(winner g of b) flat-shifted by dy=di-2
//      (cross-row bleed lands in zero columns -> exact w-shift)
__global__ __launch_bounds__(256) void k2c_shift(const unsigned short* __restrict__ Abf,
                                                 const int* __restrict__ fm_idx,
                                                 unsigned short* __restrict__ Sb) {
  int bx = blockIdx.x;  // 2560 = 16*5*32
  int g = bx & 31, di = (bx >> 5) % 5, b = bx / 160;
  int dy = di - 2;
  int c = fm_idx[b * 32 + g];
  const unsigned short* src = Abf + 128 + (size_t)(b * 128 + c) * 3840;
  unsigned short* dst = Sb + (size_t)(b * 5 + di) * 122880 + g * 3840;
  for (int q = threadIdx.x; q < 960; q += 256) {
    int p0 = q * 4;
    unsigned short h[4];
#pragma unroll
    for (int j = 0; j < 4; j++) {
      int sp = p0 + j - dy;
      h[j] = ((unsigned)sp < 3840u) ? src[sp] : (unsigned short)0;
    }
    uint2 w;
    w.x = h[0] | ((unsigned)h[1] << 16);
    w.y = h[2] | ((unsigned)h[3] << 16);
    *reinterpret_cast<uint2*>(dst + p0) = w;
  }
}

// k2t: T[b][p][g] = pad_activations(winner g of b) in pixel-major layout
__global__ __launch_bounds__(256) void k2t_transpose(const unsigned short* __restrict__ Abf,
                                                     const int* __restrict__ fm_idx,
                                                     unsigned short* __restrict__ T) {
  __shared__ int win[32];
  int b = blockIdx.x / 15, chunk = blockIdx.x % 15;  // 240 blocks
  if (threadIdx.x < 32) win[threadIdx.x] = fm_idx[b * 32 + threadIdx.x];
  __syncthreads();
  int p = chunk * 256 + threadIdx.x;
  int r = p >> 6, s2 = p & 63;
  int mr = map60(r) + 2;
  int ms = (s2 < 60) ? map60(s2) + 2 : -1;
  unsigned int out[16];
#pragma unroll
  for (int gp = 0; gp < 16; gp++) {
    unsigned short v0 = 0, v1 = 0;
    if (ms >= 0) {
      v0 = Abf[128 + ((size_t)(b * 128) + win[2 * gp]) * 3840 + mr * 64 + ms];
      v1 = Abf[128 + ((size_t)(b * 128) + win[2 * gp + 1]) * 3840 + mr * 64 + ms];
    }
    out[gp] = (unsigned)v0 | ((unsigned)v1 << 16);
  }
  uint4* dst = reinterpret_cast<uint4*>(T + (size_t)b * 122880 + (size_t)p * 32);
#pragma unroll
  for (int q = 0; q < 4; q++) {
    uint4 u;
    u.x = out[4 * q]; u.y = out[4 * q + 1]; u.z = out[4 * q + 2]; u.w = out[4 * q + 3];
    dst[q] = u;
  }
}

// k3: MFMA correlation. Block = 1 wave = (b, mtile, ntile, kchunk).
//     acc[di][dj] = sum_k S_di[g][k] * Abf_a[k + 64*(dj-2)];
//     atomicAdd into Kc[c][a][25] with c = fm_idx[b*32+g] (sums over batches).
__global__ __launch_bounds__(64) void k3_mfma(const unsigned short* __restrict__ Sb,
                                              const unsigned short* __restrict__ Abf,
                                              const int* __restrict__ fm_idx,
                                              float* __restrict__ Kc) {
  int bx = blockIdx.x;  // 1024 = b(16) x mt(2) x nt(8) x kc(4)
  int kc = bx & 3, nt = (bx >> 2) & 7, mt = (bx >> 5) & 1, b = bx >> 6;
  int lane = threadIdx.x, al = lane & 15, quad = lane >> 4;
  int g0 = mt * 16, a0 = nt * 16;
  int k0 = kc * 960;
  floatx4 acc[5][5];
#pragma unroll
  for (int i = 0; i < 5; i++)
#pragma unroll
    for (int j = 0; j < 5; j++) acc[i][j] = (floatx4){0.f, 0.f, 0.f, 0.f};
  const short8* pA[5];
#pragma unroll
  for (int di = 0; di < 5; di++)
    pA[di] = reinterpret_cast<const short8*>(
        Sb + (size_t)(b * 5 + di) * 122880 + (size_t)(g0 + al) * 3840 + k0 + quad * 8);
  const short8* pB = reinterpret_cast<const short8*>(
      Abf + 128 + (size_t)(b * 128 + a0 + al) * 3840 + k0 + quad * 8) - 16;  // -128 elems
  for (int ks = 0; ks < 30; ks++) {
    short8 afr[5], bfr[5];
#pragma unroll
    for (int d = 0; d < 5; d++) afr[d] = pA[d][0];
#pragma unroll
    for (int d = 0; d < 5; d++) bfr[d] = pB[d * 8];  // row offsets -2..+2
#pragma unroll
    for (int di = 0; di < 5; di++)
#pragma unroll
      for (int dj = 0; dj < 5; dj++)
        acc[di][dj] =
            __builtin_amdgcn_mfma_f32_16x16x32_bf16(afr[di], bfr[dj], acc[di][dj], 0, 0, 0);
#pragma unroll
    for (int d = 0; d < 5; d++) pA[d] += 4;
    pB += 4;
  }
  int crow[4];
#pragma unroll
  for (int r = 0; r < 4; r++) crow[r] = fm_idx[b * 32 + g0 + quad * 4 + r];
#pragma unroll
  for (int di = 0; di < 5; di++)
#pragma unroll
    for (int dj = 0; dj < 5; dj++) {
      int t_out = 24 - (dj * 5 + di);
#pragma unroll
      for (int r = 0; r < 4; r++) {
        atomicAdd(&Kc[((size_t)crow[r] * 128 + (a0 + al)) * 25 + t_out],
                  acc[di][dj][r] * (1.0f / 2048.0f));
      }
    }
}

// k4: W2[o][i][t] = minmax25(0.9*K[o][i][t] + 0.1*minmax25(Kc[i][o][.]))
__global__ __launch_bounds__(256) void k4_weights(const float* __restrict__ Kc,
                                                  const float* __restrict__ K,
                                                  float* __restrict__ W2) {
  int gid = blockIdx.x * 256 + threadIdx.x;  // 16384
  int o = gid >> 7, i = gid & 127;
  const float* p = Kc + ((size_t)i * 128 + o) * 25;
  float kc[25], mn = 1e30f, mx = -1e30f;
#pragma unroll
  for (int t = 0; t < 25; t++) {
    kc[t] = p[t];
    mn = fminf(mn, kc[t]);
    mx = fmaxf(mx, kc[t]);
  }
  float d1 = mx - mn + EPSF;
  const float* kp = K + ((size_t)o * 128 + i) * 25;
  float k2[25], mn2 = 1e30f, mx2 = -1e30f;
#pragma unroll
  for (int t = 0; t < 25; t++) {
    k2[t] = 0.9f * kp[t] + 0.1f * ((kc[t] - mn) / d1);
    mn2 = fminf(mn2, k2[t]);
    mx2 = fmaxf(mx2, k2[t]);
  }
  float d2 = mx2 - mn2 + EPSF;
#pragma unroll
  for (int t = 0; t < 25; t++) W2[(size_t)gid * 25 + t] = (k2[t] - mn2) / d2;
}

// k4b: W2g[b][t][f][g] bf16 = W2[o_f][i_g][t] (per-batch winner gather)
__global__ __launch_bounds__(256) void k4b_gather(const float* __restrict__ W2,
                                                  const int* __restrict__ fm_idx,
                                                  unsigned short* __restrict__ W2g) {
  int tid = blockIdx.x * 256 + threadIdx.x;  // 16384
  int b = tid >> 10, f = (tid >> 5) & 31, g = tid & 31;
  int o = fm_idx[b * 32 + f], i = fm_idx[b * 32 + g];
  const float* src = W2 + ((size_t)o * 128 + i) * 25;
#pragma unroll
  for (int t = 0; t < 25; t++)
    W2g[((size_t)((b * 25 + t) * 32 + f) << 5) + g] = f2bf(src[t]);
}

// k5: MFMA conv + gather epilogue. Block = 1 wave = (b, mtile, rowgroup of 4).
__global__ __launch_bounds__(64) void k5_mfma(const unsigned short* __restrict__ W2g,
                                              const unsigned short* __restrict__ T,
                                              const unsigned short* __restrict__ Abf,
                                              const int* __restrict__ fm_idx,
                                              float* __restrict__ O) {
  int bx = blockIdx.x;  // 448 = b(16) x mt(2) x rg(14)
  int rg = bx % 14;
  int mtb = bx / 14;
  int mt = mtb & 1, b = mtb >> 1;
  int lane = threadIdx.x, al = lane & 15, quad = lane >> 4;
  int fm = mt * 16 + al;
  short8 afr[25];
#pragma unroll
  for (int t = 0; t < 25; t++)
    afr[t] = *reinterpret_cast<const short8*>(
        W2g + ((size_t)((b * 25 + t) * 32 + fm) << 5) + quad * 8);
  int orow[4];
#pragma unroll
  for (int r = 0; r < 4; r++) orow[r] = fm_idx[b * 32 + mt * 16 + quad * 4 + r];
  const unsigned short* Tb = T + (size_t)b * 122880;
  for (int rr = 0; rr < 4; rr++) {
    int row = 2 + rg * 4 + rr;
    for (int pair = 0; pair < 2; pair++) {
      int px0 = row * 64 + pair * 32 + al;
      floatx4 acca = (floatx4){0.f, 0.f, 0.f, 0.f};
      floatx4 accb = (floatx4){0.f, 0.f, 0.f, 0.f};
#pragma unroll
      for (int t = 0; t < 25; t++) {
        int off = (t / 5 - 2) * 64 + (t % 5) - 2;
        const short8* pb = reinterpret_cast<const short8*>(
            Tb + (ptrdiff_t)(px0 + off) * 32 + quad * 8);
        short8 b0 = pb[0];
        short8 b1 = pb[64];  // +16 px
        acca = __builtin_amdgcn_mfma_f32_16x16x32_bf16(afr[t], b0, acca, 0, 0, 0);
        accb = __builtin_amdgcn_mfma_f32_16x16x32_bf16(afr[t], b1, accb, 0, 0, 0);
      }
      int h = row - 2;
#pragma unroll
      for (int half = 0; half < 2; half++) {
        floatx4 acc = half ? accb : acca;
        int cc = pair * 32 + half * 16 + al;
        if (cc >= 2 && cc < 58) {
          int w = cc - 2;
          int px = row * 64 + cc;
#pragma unroll
          for (int r = 0; r < 4; r++) {
            int f = mt * 16 + quad * 4 + r;
            float base = bf2f(Abf[128 + (size_t)(b * 128 + orow[r]) * 3840 + px]);
            O[(size_t)(b * 32 + f) * 3136 + h * 56 + w] = base + acc[r] * (0.1f / 32.0f);
          }
        }
      }
    }
  }
}

extern "C" void kernel_launch(void* const* d_in, const int* in_sizes, int n_in,
                              void* d_out, int out_size, void* d_ws, size_t ws_size,
                              hipStream_t stream) {
  const float* A = (const float*)d_in[0];
  const float* K = (const float*)d_in[1];
  const float* noise = (const float*)d_in[2];
  float* O = (float*)d_out;

  float* ws = (float*)d_ws;
  unsigned short* Abf = (unsigned short*)ws;              // 7,864,576 us = 3,932,288 f
  float* s = ws + 3932288;                                // 2,048
  int* fm_idx = (int*)(ws + 3934336);                     // 512 (+pad)
  float* Kc = ws + 3934976;                               // 409,600  [c][a][25]
  float* W2 = ws + 4344576;                               // 409,600
  unsigned short* W2g = (unsigned short*)(ws + 4754176);  // 409,600 us = 204,800 f
  unsigned short* T = (unsigned short*)(ws + 4958976);    // 1,966,080 us = 983,040 f
  unsigned short* Sb = (unsigned short*)(ws + 5942016);   // 9,830,400 us = 4,915,200 f
  // end: 10,857,216 floats = 43.4 MB (< R1's proven-good 47.5 MB)

  k1_build<<<2048, 256, 0, stream>>>(A, noise, Abf, s);
  k2_winners<<<1, 512, 0, stream>>>(s, fm_idx, Abf);
  hipMemsetAsync(Kc, 0, 409600 * sizeof(float), stream);
  k2c_shift<<<2560, 256, 0, stream>>>(Abf, fm_idx, Sb);
  k2t_transpose<<<240, 256, 0, stream>>>(Abf, fm_idx, T);
  k3_mfma<<<1024, 64, 0, stream>>>(Sb, Abf, fm_idx, Kc);
  k4_weights<<<64, 256, 0, stream>>>(Kc, K, W2);
  k4b_gather<<<64, 256, 0, stream>>>(W2, fm_idx, W2g);
  k5_mfma<<<448, 64, 0, stream>>>(W2g, T, Abf, fm_idx, O);
}

// Round 7
// 182.077 us; speedup vs baseline: 2.7669x; 2.7669x over previous
//
#include <hip/hip_runtime.h>

// LaterallyConnectedLayer: B=16, NUM_FM=32, N_REPL=4, C=128, H=W=56, K_SZ=5
// Algebra:
//  - softmax map sums to 1 -> first conv never affects winners -> skipped
//  - winner sparsity: K_change and final conv only touch 32 of 128 channels
//  - padding = index remaps; activations in zero-ring-padded [60][64] frames
// R6: k3 atomics (210 MB HBM write-through, 368 us) -> 4-wave blocks with
//     LDS cross-wave reduce + plain stores into Kc_b[b][g][a][25]; k4 back to
//     R1-proven cmask batch-sum. W2/W2g alias Sb region (lifetimes disjoint)
//     to stay at 45.9 MB < proven-good 47.5 MB.

typedef __attribute__((ext_vector_type(8))) short short8;
typedef __attribute__((ext_vector_type(4))) float floatx4;

#define EPSF 1e-10f

__device__ __forceinline__ int map60(int r) {
  return r < 4 ? 5 - r : (r < 56 ? r - 2 : 109 - r);
}
__device__ __forceinline__ unsigned short f2bf(float x) {
  unsigned int u = __float_as_uint(x);
  u += 0x7fff + ((u >> 16) & 1);
  return (unsigned short)(u >> 16);
}
__device__ __forceinline__ float bf2f(unsigned int h) {
  return __uint_as_float((h & 0xffffu) << 16);
}

// k1: Abf[128 + bc*3840 + p] = bf16 zero-ring relu(A_sym + 0.1*noise);
//     s[bc] = fp32 interior sum (pre-rounding)
__global__ __launch_bounds__(256) void k1_build(const float* __restrict__ A,
                                                const float* __restrict__ noise,
                                                unsigned short* __restrict__ Abf,
                                                float* __restrict__ s) {
  int bc = blockIdx.x;
  int b = bc >> 7, c = bc & 127;
  int fm = c & 31;
  const float* Abase = A + (size_t)(b * 32 + fm) * 3136;
  const float* nz = noise + (size_t)bc * 3136;
  unsigned short* outb = Abf + 128 + (size_t)bc * 3840;
  float local = 0.f;
  for (int idx = threadIdx.x; idx < 3840; idx += 256) {
    int r = idx >> 6, col = idx & 63;
    int h = r - 2, w = col - 2;
    float v = 0.f;
    if ((unsigned)h < 56u && (unsigned)w < 56u) {
      int hh = h < 2 ? 3 - h : (h >= 54 ? 107 - h : h);
      int ww = w < 2 ? 3 - w : (w >= 54 ? 107 - w : w);
      v = fmaxf(Abase[hh * 56 + ww] + 0.1f * nz[h * 56 + w], 0.f);
      local += v;
    }
    outb[idx] = f2bf(v);
  }
  int lane = threadIdx.x & 63, wid = threadIdx.x >> 6;
  float v = local;
  for (int off = 32; off; off >>= 1) v += __shfl_down(v, off, 64);
  __shared__ float red[4];
  if (lane == 0) red[wid] = v;
  __syncthreads();
  if (threadIdx.x == 0) s[bc] = red[0] + red[1] + red[2] + red[3];
}

// k2: winners + per-channel batch bitmask + zero Abf guard rings
__global__ __launch_bounds__(512) void k2_winners(const float* __restrict__ s,
                                                  int* __restrict__ fm_idx,
                                                  int* __restrict__ cmask,
                                                  unsigned short* __restrict__ Abf) {
  int t = threadIdx.x;
  {
    int b = t >> 5, f = t & 31;
    float best = s[b * 128 + f];
    int bn = 0;
    for (int n = 1; n < 4; n++) {
      float v = s[b * 128 + n * 32 + f];
      if (v > best) { best = v; bn = n; }
    }
    fm_idx[t] = bn * 32 + f;
  }
  if (t < 128) Abf[t] = 0;
  if (t >= 384) Abf[128 + 7864320 + (t - 384)] = 0;
  __syncthreads();
  if (t < 128) {
    int m = 0;
    for (int b = 0; b < 16; b++)
      if (fm_idx[b * 32 + (t & 31)] == t) m |= (1 << b);
    cmask[t] = m;
  }
}

// k2c: Sb[b][di][g][3840] = Abf(winner g of b) flat-shifted by dy=di-2
__global__ __launch_bounds__(256) void k2c_shift(const unsigned short* __restrict__ Abf,
                                                 const int* __restrict__ fm_idx,
                                                 unsigned short* __restrict__ Sb) {
  int bx = blockIdx.x;  // 2560 = 16*5*32
  int g = bx & 31, di = (bx >> 5) % 5, b = bx / 160;
  int dy = di - 2;
  int c = fm_idx[b * 32 + g];
  const unsigned short* src = Abf + 128 + (size_t)(b * 128 + c) * 3840;
  unsigned short* dst = Sb + (size_t)(b * 5 + di) * 122880 + g * 3840;
  for (int q = threadIdx.x; q < 960; q += 256) {
    int p0 = q * 4;
    unsigned short h[4];
#pragma unroll
    for (int j = 0; j < 4; j++) {
      int sp = p0 + j - dy;
      h[j] = ((unsigned)sp < 3840u) ? src[sp] : (unsigned short)0;
    }
    uint2 w;
    w.x = h[0] | ((unsigned)h[1] << 16);
    w.y = h[2] | ((unsigned)h[3] << 16);
    *reinterpret_cast<uint2*>(dst + p0) = w;
  }
}

// k2t: T[b][p][g] = pad_activations(winner g of b) in pixel-major layout
__global__ __launch_bounds__(256) void k2t_transpose(const unsigned short* __restrict__ Abf,
                                                     const int* __restrict__ fm_idx,
                                                     unsigned short* __restrict__ T) {
  __shared__ int win[32];
  int b = blockIdx.x / 15, chunk = blockIdx.x % 15;  // 240 blocks
  if (threadIdx.x < 32) win[threadIdx.x] = fm_idx[b * 32 + threadIdx.x];
  __syncthreads();
  int p = chunk * 256 + threadIdx.x;
  int r = p >> 6, s2 = p & 63;
  int mr = map60(r) + 2;
  int ms = (s2 < 60) ? map60(s2) + 2 : -1;
  unsigned int out[16];
#pragma unroll
  for (int gp = 0; gp < 16; gp++) {
    unsigned short v0 = 0, v1 = 0;
    if (ms >= 0) {
      v0 = Abf[128 + ((size_t)(b * 128) + win[2 * gp]) * 3840 + mr * 64 + ms];
      v1 = Abf[128 + ((size_t)(b * 128) + win[2 * gp + 1]) * 3840 + mr * 64 + ms];
    }
    out[gp] = (unsigned)v0 | ((unsigned)v1 << 16);
  }
  uint4* dst = reinterpret_cast<uint4*>(T + (size_t)b * 122880 + (size_t)p * 32);
#pragma unroll
  for (int q = 0; q < 4; q++) {
    uint4 u;
    u.x = out[4 * q]; u.y = out[4 * q + 1]; u.z = out[4 * q + 2]; u.w = out[4 * q + 3];
    dst[q] = u;
  }
}

// k3: MFMA correlation, no atomics. Block = (b, mtile, ntile), 4 waves; wave w
//     owns K-chunk w (30 ksteps). LDS reduce across waves; plain stores into
//     Kc_b[b][g][a][25] (tap-flipped, /2048).
__global__ __launch_bounds__(256, 1) void k3_mfma(const unsigned short* __restrict__ Sb,
                                                  const unsigned short* __restrict__ Abf,
                                                  float* __restrict__ Kc_b) {
  int bx = blockIdx.x;  // 256 = b(16) x mt(2) x nt(8)
  int nt = bx & 7, mt = (bx >> 3) & 1, b = bx >> 4;
  int wave = threadIdx.x >> 6, lane = threadIdx.x & 63;
  int al = lane & 15, quad = lane >> 4;
  int g0 = mt * 16, a0 = nt * 16;
  int k0 = wave * 960;
  floatx4 acc[5][5];
#pragma unroll
  for (int i = 0; i < 5; i++)
#pragma unroll
    for (int j = 0; j < 5; j++) acc[i][j] = (floatx4){0.f, 0.f, 0.f, 0.f};
  const short8* pA[5];
#pragma unroll
  for (int di = 0; di < 5; di++)
    pA[di] = reinterpret_cast<const short8*>(
        Sb + (size_t)(b * 5 + di) * 122880 + (size_t)(g0 + al) * 3840 + k0 + quad * 8);
  const short8* pB = reinterpret_cast<const short8*>(
      Abf + 128 + (size_t)(b * 128 + a0 + al) * 3840 + k0 + quad * 8) - 16;  // -128 elems
  for (int ks = 0; ks < 30; ks++) {
    short8 afr[5], bfr[5];
#pragma unroll
    for (int d = 0; d < 5; d++) afr[d] = pA[d][0];
#pragma unroll
    for (int d = 0; d < 5; d++) bfr[d] = pB[d * 8];  // row offsets -2..+2
#pragma unroll
    for (int di = 0; di < 5; di++)
#pragma unroll
      for (int dj = 0; dj < 5; dj++)
        acc[di][dj] =
            __builtin_amdgcn_mfma_f32_16x16x32_bf16(afr[di], bfr[dj], acc[di][dj], 0, 0, 0);
#pragma unroll
    for (int d = 0; d < 5; d++) pA[d] += 4;
    pB += 4;
  }
  // cross-wave reduce: red[lane][100]
  __shared__ float red[6400];
  float* myrow = red + lane * 100;
  if (wave == 0) {
#pragma unroll
    for (int di = 0; di < 5; di++)
#pragma unroll
      for (int dj = 0; dj < 5; dj++)
#pragma unroll
        for (int r = 0; r < 4; r++) myrow[(di * 5 + dj) * 4 + r] = acc[di][dj][r];
  }
  __syncthreads();
#pragma unroll
  for (int w = 1; w < 4; w++) {
    if (wave == w) {
#pragma unroll
      for (int di = 0; di < 5; di++)
#pragma unroll
        for (int dj = 0; dj < 5; dj++)
#pragma unroll
          for (int r = 0; r < 4; r++) myrow[(di * 5 + dj) * 4 + r] += acc[di][dj][r];
    }
    __syncthreads();
  }
  if (wave == 0) {
#pragma unroll
    for (int di = 0; di < 5; di++)
#pragma unroll
      for (int dj = 0; dj < 5; dj++) {
        int t_out = 24 - (dj * 5 + di);
#pragma unroll
        for (int r = 0; r < 4; r++) {
          int g = g0 + quad * 4 + r;
          Kc_b[(((size_t)b * 32 + g) * 128 + (a0 + al)) * 25 + t_out] =
              myrow[(di * 5 + dj) * 4 + r] * (1.0f / 2048.0f);
        }
      }
  }
}

// k4: W2[o][i][t] = minmax25(0.9*K[o][i][t] + 0.1*minmax25(sum_b Kc_b[b][i&31][o][.]))
__global__ __launch_bounds__(256) void k4_weights(const float* __restrict__ Kc_b,
                                                  const float* __restrict__ K,
                                                  const int* __restrict__ cmask,
                                                  float* __restrict__ W2) {
  int gid = blockIdx.x * 256 + threadIdx.x;  // 16384
  int o = gid >> 7, i = gid & 127;
  int m = cmask[i];
  float kc[25];
#pragma unroll
  for (int t = 0; t < 25; t++) kc[t] = 0.f;
  for (int b = 0; b < 16; b++) {
    if ((m >> b) & 1) {
      const float* p = Kc_b + (((size_t)b * 32 + (i & 31)) * 128 + o) * 25;
#pragma unroll
      for (int t = 0; t < 25; t++) kc[t] += p[t];
    }
  }
  float mn = 1e30f, mx = -1e30f;
#pragma unroll
  for (int t = 0; t < 25; t++) { mn = fminf(mn, kc[t]); mx = fmaxf(mx, kc[t]); }
  float d1 = mx - mn + EPSF;
  const float* kp = K + ((size_t)o * 128 + i) * 25;
  float k2[25], mn2 = 1e30f, mx2 = -1e30f;
#pragma unroll
  for (int t = 0; t < 25; t++) {
    k2[t] = 0.9f * kp[t] + 0.1f * ((kc[t] - mn) / d1);
    mn2 = fminf(mn2, k2[t]);
    mx2 = fmaxf(mx2, k2[t]);
  }
  float d2 = mx2 - mn2 + EPSF;
#pragma unroll
  for (int t = 0; t < 25; t++) W2[(size_t)gid * 25 + t] = (k2[t] - mn2) / d2;
}

// k4b: W2g[b][t][f][g] bf16 = W2[o_f][i_g][t] (per-batch winner gather)
__global__ __launch_bounds__(256) void k4b_gather(const float* __restrict__ W2,
                                                  const int* __restrict__ fm_idx,
                                                  unsigned short* __restrict__ W2g) {
  int tid = blockIdx.x * 256 + threadIdx.x;  // 16384
  int b = tid >> 10, f = (tid >> 5) & 31, g = tid & 31;
  int o = fm_idx[b * 32 + f], i = fm_idx[b * 32 + g];
  const float* src = W2 + ((size_t)o * 128 + i) * 25;
#pragma unroll
  for (int t = 0; t < 25; t++)
    W2g[((size_t)((b * 25 + t) * 32 + f) << 5) + g] = f2bf(src[t]);
}

// k5: MFMA conv + gather epilogue. Block = 1 wave = (b, mtile, rowgroup of 4).
__global__ __launch_bounds__(64) void k5_mfma(const unsigned short* __restrict__ W2g,
                                              const unsigned short* __restrict__ T,
                                              const unsigned short* __restrict__ Abf,
                                              const int* __restrict__ fm_idx,
                                              float* __restrict__ O) {
  int bx = blockIdx.x;  // 448 = b(16) x mt(2) x rg(14)
  int rg = bx % 14;
  int mtb = bx / 14;
  int mt = mtb & 1, b = mtb >> 1;
  int lane = threadIdx.x, al = lane & 15, quad = lane >> 4;
  int fm = mt * 16 + al;
  short8 afr[25];
#pragma unroll
  for (int t = 0; t < 25; t++)
    afr[t] = *reinterpret_cast<const short8*>(
        W2g + ((size_t)((b * 25 + t) * 32 + fm) << 5) + quad * 8);
  int orow[4];
#pragma unroll
  for (int r = 0; r < 4; r++) orow[r] = fm_idx[b * 32 + mt * 16 + quad * 4 + r];
  const unsigned short* Tb = T + (size_t)b * 122880;
  for (int rr = 0; rr < 4; rr++) {
    int row = 2 + rg * 4 + rr;
    for (int pair = 0; pair < 2; pair++) {
      int px0 = row * 64 + pair * 32 + al;
      floatx4 acca = (floatx4){0.f, 0.f, 0.f, 0.f};
      floatx4 accb = (floatx4){0.f, 0.f, 0.f, 0.f};
#pragma unroll
      for (int t = 0; t < 25; t++) {
        int off = (t / 5 - 2) * 64 + (t % 5) - 2;
        const short8* pb = reinterpret_cast<const short8*>(
            Tb + (ptrdiff_t)(px0 + off) * 32 + quad * 8);
        short8 b0 = pb[0];
        short8 b1 = pb[64];  // +16 px
        acca = __builtin_amdgcn_mfma_f32_16x16x32_bf16(afr[t], b0, acca, 0, 0, 0);
        accb = __builtin_amdgcn_mfma_f32_16x16x32_bf16(afr[t], b1, accb, 0, 0, 0);
      }
      int h = row - 2;
#pragma unroll
      for (int half = 0; half < 2; half++) {
        floatx4 acc = half ? accb : acca;
        int cc = pair * 32 + half * 16 + al;
        if (cc >= 2 && cc < 58) {
          int w = cc - 2;
          int px = row * 64 + cc;
#pragma unroll
          for (int r = 0; r < 4; r++) {
            int f = mt * 16 + quad * 4 + r;
            float base = bf2f(Abf[128 + (size_t)(b * 128 + orow[r]) * 3840 + px]);
            O[(size_t)(b * 32 + f) * 3136 + h * 56 + w] = base + acc[r] * (0.1f / 32.0f);
          }
        }
      }
    }
  }
}

extern "C" void kernel_launch(void* const* d_in, const int* in_sizes, int n_in,
                              void* d_out, int out_size, void* d_ws, size_t ws_size,
                              hipStream_t stream) {
  const float* A = (const float*)d_in[0];
  const float* K = (const float*)d_in[1];
  const float* noise = (const float*)d_in[2];
  float* O = (float*)d_out;

  float* ws = (float*)d_ws;
  unsigned short* Abf = (unsigned short*)ws;              // 7,864,576 us = 3,932,288 f
  float* s = ws + 3932288;                                // 2,048
  int* fm_idx = (int*)(ws + 3934336);                     // 512
  int* cmask = (int*)(ws + 3934848);                      // 128
  float* Kc_b = ws + 3934976;                             // 1,638,400  [b][g][a][25]
  unsigned short* T = (unsigned short*)(ws + 5573376);    // 1,966,080 us = 983,040 f
  unsigned short* Sb = (unsigned short*)(ws + 6556416);   // 9,830,400 us = 4,915,200 f
  // W2/W2g alias the (dead-after-k3) Sb region:
  float* W2 = ws + 6556416;                               // 409,600
  unsigned short* W2g = (unsigned short*)(ws + 6966016);  // 409,600 us = 204,800 f
  // end: 11,471,616 floats = 45.9 MB (< R1's proven-good 47.5 MB)

  k1_build<<<2048, 256, 0, stream>>>(A, noise, Abf, s);
  k2_winners<<<1, 512, 0, stream>>>(s, fm_idx, cmask, Abf);
  k2c_shift<<<2560, 256, 0, stream>>>(Abf, fm_idx, Sb);
  k2t_transpose<<<240, 256, 0, stream>>>(Abf, fm_idx, T);
  k3_mfma<<<256, 256, 0, stream>>>(Sb, Abf, Kc_b);
  k4_weights<<<64, 256, 0, stream>>>(Kc_b, K, cmask, W2);
  k4b_gather<<<64, 256, 0, stream>>>(W2, fm_idx, W2g);
  k5_mfma<<<448, 64, 0, stream>>>(W2g, T, Abf, fm_idx, O);
}